// Round 1
// baseline (252.799 us; speedup 1.0000x reference)
//
#include <hip/hip_runtime.h>
#include <hip/hip_bf16.h>

#define CC 64
#define HH 128
#define WW 128
#define OO 576   // C * K * K
#define HW (HH * WW)

typedef __attribute__((ext_vector_type(8))) short short8;
typedef __attribute__((ext_vector_type(4))) float floatx4;

__device__ __forceinline__ unsigned short f2bf(float f) {
    unsigned u = __float_as_uint(f);
    u = (u + 0x7FFFu + ((u >> 16) & 1u)) >> 16;   // RTNE
    return (unsigned short)u;
}

// Pre-convert W_gen (576x64 fp32) -> bf16 in workspace
__global__ void ACDA_wconv_kernel(const float* __restrict__ Wg,
                                  unsigned short* __restrict__ Wb) {
    int i = blockIdx.x * 256 + threadIdx.x;
    if (i < OO * CC) Wb[i] = f2bf(Wg[i]);
}

// 256-thread block = 4 waves. Wave wv owns 16 output channels x 64-pixel
// segment (same work as the old 1-wave block; 4 old blocks merged).
// No __syncthreads anywhere: each wave uses a PRIVATE FbufT slice, and
// intra-wave DS ordering guarantees the write->read dependency.
// Rationale: 1-wave WGs were capped by the per-CU workgroup-slot limit
// (~16 waves/CU, 34% occupancy measured). 4-wave WGs allow 8 blocks/CU
// = 32 waves/CU at VGPR<=64, LDS 20480*8 = 160 KiB exactly.
__global__ __launch_bounds__(256, 8) void ACDA_main_kernel(
    const float* __restrict__ x, const unsigned short* __restrict__ Wb,
    const float* __restrict__ bg, float* __restrict__ out)
{
    // Transposed filter buffer: [wave][pixel][filter-row], row stride 20
    // floats (pad 16->20). Write: one ds_write_b128 per MFMA acc (4 rows of
    // one pixel). Read: 4x ds_read_b128 per chunk (pixel = lane).
    // Bank starts for 8 consecutive lanes: (20*l)%32 = {0,20,8,28,16,4,24,12}
    // -> covers all 32 banks, conflict-free both phases.
    __shared__ float FbufT[4][64][20];   // 20480 B

    const int tid  = threadIdx.x;
    const int lane = tid & 63;
    const int wv   = tid >> 6;       // which 16-channel group
    const int quad = lane >> 4;
    const int l16  = lane & 15;

    // Bijective XCD swizzle: 2048 blocks, 8 XCDs, 256 contiguous work items
    // per XCD => each XCD streams exactly one batch image (4.2 MB ~ L2).
    const int bid = blockIdx.x;
    const int wk  = (bid & 7) * 256 + (bid >> 3);
    const int seg = wk & 1;
    const int h   = (wk >> 1) & 127;
    const int b   = wk >> 8;
    const int w0  = seg << 6;

    const float* xb = x + (size_t)b * CC * HW;

    // ---- B fragments (X tile, bf16) held in registers for all 9 chunks ----
    // B[k][n]: n = lane&15 (pixel), k = quad*8 + j (channel)
    short8 bfrag[4][2];
#pragma unroll
    for (int nt = 0; nt < 4; ++nt) {
#pragma unroll
        for (int ks = 0; ks < 2; ++ks) {
            short8 v;
            const int w = w0 + nt * 16 + l16;
#pragma unroll
            for (int j = 0; j < 8; j += 2) {
                const int c = ks * 32 + quad * 8 + j;
                float f0 = xb[(c * HH + h) * WW + w];
                float f1 = xb[((c + 1) * HH + h) * WW + w];
                __hip_bfloat162 p = __float22bfloat162_rn(make_float2(f0, f1));
                unsigned u;
                __builtin_memcpy(&u, &p, 4);
                v[j]     = (short)(u & 0xffffu);
                v[j + 1] = (short)(u >> 16);
            }
            bfrag[nt][ks] = v;
        }
    }

    // ---- combine-phase per-lane precompute (clamped cols/rows + kill masks) ----
    int wA = w0 + lane - 1; bool badA = (wA < 0);   if (badA) wA = 0;
    int wB = w0 + lane;
    int wC = w0 + lane + 1; bool badC = (wC > 127); if (badC) wC = 127;
    int rt[3]; bool rbad[3];
#pragma unroll
    for (int di = 0; di < 3; ++di) {
        int rr = h + di - 1;
        rbad[di] = (rr < 0) || (rr > 127);
        rr = rr < 0 ? 0 : (rr > 127 ? 127 : rr);
        rt[di] = rr * WW;
    }
    const int wsel[3]  = {wA, wB, wC};
    const bool wbad[3] = {badA, false, badC};
    const int soffC = wv * 16 * HW;   // channel-group base for patch loads
    int  pb[3][3]; bool bad[3][3];
#pragma unroll
    for (int di = 0; di < 3; ++di)
#pragma unroll
        for (int dj = 0; dj < 3; ++dj) {
            pb[di][dj]  = soffC + rt[di] + wsel[dj];
            bad[di][dj] = rbad[di] || wbad[dj];
        }

    float oacc[16];
#pragma unroll
    for (int i = 0; i < 16; ++i) oacc[i] = 0.f;

    // ---- 9 m-chunks of 16 filter rows each (wave owns o in [144wv, +144)) ----
#pragma unroll
    for (int t = 0; t < 9; ++t) {
        const int obase = wv * 144 + t * 16;
        // A[m][k]: m = lane&15 (filter row), k = quad*8 + j
        const unsigned short* wrow = Wb + (obase + l16) * CC + quad * 8;
        short8 a0 = *(const short8*)(wrow);
        short8 a1 = *(const short8*)(wrow + 32);
#pragma unroll
        for (int nt = 0; nt < 4; ++nt) {
            floatx4 z = {0.f, 0.f, 0.f, 0.f};
            z = __builtin_amdgcn_mfma_f32_16x16x32_bf16(a0, bfrag[nt][0], z, 0, 0, 0);
            z = __builtin_amdgcn_mfma_f32_16x16x32_bf16(a1, bfrag[nt][1], z, 0, 0, 0);
            // C[m][n]: n(col) = lane&15, m(row) = quad*4 + reg
            // -> transposed store: pixel nt*16+l16, rows quad*4..+3, ONE b128
            *(floatx4*)&FbufT[wv][nt * 16 + l16][quad * 4] = z;
        }

        // combine: each lane = one pixel (p = lane), 16 filter rows via
        // 4x ds_read_b128 (in-order DS within the wave orders write->read)
#pragma unroll
        for (int g = 0; g < 4; ++g) {
            floatx4 f4 = *(const floatx4*)&FbufT[wv][lane][g * 4];
#pragma unroll
            for (int rr = 0; rr < 4; ++rr) {
                const int r     = g * 4 + rr;        // all compile-time
                const int idx   = t * 16 + r;
                const int c_rel = idx / 9;
                const int kk    = idx - 9 * c_rel;
                const int di    = kk / 3;
                const int dj    = kk - 3 * di;
                float fv = f4[rr] + bg[obase + r];   // bias: wave-uniform s_load
                fv = fmaxf(fv, 0.f);
                float pv = xb[pb[di][dj] + c_rel * HW];
                if (bad[di][dj]) pv = 0.f;
                oacc[c_rel] = fmaf(fv, pv, oacc[c_rel]);
            }
        }
    }

    float* ob = out + (size_t)b * CC * HW + h * WW + w0 + lane;
#pragma unroll
    for (int i = 0; i < 16; ++i)
        ob[(wv * 16 + i) * HW] = oacc[i];
}

extern "C" void kernel_launch(void* const* d_in, const int* in_sizes, int n_in,
                              void* d_out, int out_size, void* d_ws, size_t ws_size,
                              hipStream_t stream) {
    const float* x  = (const float*)d_in[0];
    const float* Wg = (const float*)d_in[1];
    const float* bg = (const float*)d_in[2];
    float* out = (float*)d_out;
    unsigned short* Wb = (unsigned short*)d_ws;   // 576*64*2 = 73728 B

    ACDA_wconv_kernel<<<dim3((OO * CC + 255) / 256), dim3(256), 0, stream>>>(Wg, Wb);
    ACDA_main_kernel<<<dim3(8 * 128 * 2), dim3(256), 0, stream>>>(x, Wb, bg, out);
}

// Round 3
// 118.632 us; speedup vs baseline: 2.1310x; 2.1310x over previous
//
#include <hip/hip_runtime.h>
#include <hip/hip_bf16.h>

#define CC 64
#define HH 128
#define WW 128
#define OO 576   // C * K * K
#define HW (HH * WW)

typedef __attribute__((ext_vector_type(8))) short short8;
typedef __attribute__((ext_vector_type(4))) float floatx4;

__device__ __forceinline__ unsigned short f2bf(float f) {
    unsigned u = __float_as_uint(f);
    u = (u + 0x7FFFu + ((u >> 16) & 1u)) >> 16;   // RTNE
    return (unsigned short)u;
}

// Pre-convert W_gen (576x64 fp32) -> bf16 in workspace
__global__ void ACDA_wconv_kernel(const float* __restrict__ Wg,
                                  unsigned short* __restrict__ Wb) {
    int i = blockIdx.x * 256 + threadIdx.x;
    if (i < OO * CC) Wb[i] = f2bf(Wg[i]);
}

// 256-thread block = 4 waves. Wave wv owns 16 output channels x 64-pixel
// segment. No __syncthreads: each wave uses a PRIVATE FbufT slice; intra-wave
// DS ordering guarantees the write->read dependency.
//
// launch_bounds NOTE (round-1 post-mortem): (256, 8) capped the unified
// VGPR/AGPR file at 64/wave; the allocator split it and SPILLED (~190 MB of
// scratch writes showed up in WRITE_SIZE, VGPR_Count=32, 3.7x slower).
// (256, 4) caps at 128 -> natural allocation ~64, no spills; occupancy is
// then LDS-limited: 160K / 20480 = 8 blocks/CU = 32 waves/CU (100%).
__global__ __launch_bounds__(256, 4) void ACDA_main_kernel(
    const float* __restrict__ x, const unsigned short* __restrict__ Wb,
    const float* __restrict__ bg, float* __restrict__ out)
{
    // Transposed filter buffer: [wave][pixel][filter-row], row stride 20
    // floats (pad 16->20). Write: one ds_write_b128 per MFMA acc (4 rows of
    // one pixel). Read: 4x ds_read_b128 per chunk (pixel = lane).
    // Bank starts for 8 consecutive lanes: (20*l)%32 = {0,20,8,28,16,4,24,12}
    // -> covers all 32 banks, conflict-free both phases.
    __shared__ float FbufT[4][64][20];   // 20480 B

    const int tid  = threadIdx.x;
    const int lane = tid & 63;
    const int wv   = tid >> 6;       // which 16-channel group
    const int quad = lane >> 4;
    const int l16  = lane & 15;

    // Bijective XCD swizzle: 2048 blocks, 8 XCDs, 256 contiguous work items
    // per XCD => each XCD streams exactly one batch image (4.2 MB ~ L2).
    const int bid = blockIdx.x;
    const int wk  = (bid & 7) * 256 + (bid >> 3);
    const int seg = wk & 1;
    const int h   = (wk >> 1) & 127;
    const int b   = wk >> 8;
    const int w0  = seg << 6;

    const float* xb = x + (size_t)b * CC * HW;

    // ---- B fragments (X tile, bf16) held in registers for all 9 chunks ----
    // B[k][n]: n = lane&15 (pixel), k = quad*8 + j (channel)
    short8 bfrag[4][2];
#pragma unroll
    for (int nt = 0; nt < 4; ++nt) {
#pragma unroll
        for (int ks = 0; ks < 2; ++ks) {
            short8 v;
            const int w = w0 + nt * 16 + l16;
#pragma unroll
            for (int j = 0; j < 8; j += 2) {
                const int c = ks * 32 + quad * 8 + j;
                float f0 = xb[(c * HH + h) * WW + w];
                float f1 = xb[((c + 1) * HH + h) * WW + w];
                __hip_bfloat162 p = __float22bfloat162_rn(make_float2(f0, f1));
                unsigned u;
                __builtin_memcpy(&u, &p, 4);
                v[j]     = (short)(u & 0xffffu);
                v[j + 1] = (short)(u >> 16);
            }
            bfrag[nt][ks] = v;
        }
    }

    // ---- combine-phase per-lane precompute (clamped cols/rows + kill masks) ----
    int wA = w0 + lane - 1; bool badA = (wA < 0);   if (badA) wA = 0;
    int wB = w0 + lane;
    int wC = w0 + lane + 1; bool badC = (wC > 127); if (badC) wC = 127;
    int rt[3]; bool rbad[3];
#pragma unroll
    for (int di = 0; di < 3; ++di) {
        int rr = h + di - 1;
        rbad[di] = (rr < 0) || (rr > 127);
        rr = rr < 0 ? 0 : (rr > 127 ? 127 : rr);
        rt[di] = rr * WW;
    }
    const int wsel[3]  = {wA, wB, wC};
    const bool wbad[3] = {badA, false, badC};
    const int soffC = wv * 16 * HW;   // channel-group base for patch loads
    int  pb[3][3]; bool bad[3][3];
#pragma unroll
    for (int di = 0; di < 3; ++di)
#pragma unroll
        for (int dj = 0; dj < 3; ++dj) {
            pb[di][dj]  = soffC + rt[di] + wsel[dj];
            bad[di][dj] = rbad[di] || wbad[dj];
        }

    float oacc[16];
#pragma unroll
    for (int i = 0; i < 16; ++i) oacc[i] = 0.f;

    // ---- 9 m-chunks of 16 filter rows each (wave owns o in [144wv, +144)) ----
#pragma unroll
    for (int t = 0; t < 9; ++t) {
        const int obase = wv * 144 + t * 16;
        // A[m][k]: m = lane&15 (filter row), k = quad*8 + j
        const unsigned short* wrow = Wb + (obase + l16) * CC + quad * 8;
        short8 a0 = *(const short8*)(wrow);
        short8 a1 = *(const short8*)(wrow + 32);
#pragma unroll
        for (int nt = 0; nt < 4; ++nt) {
            floatx4 z = {0.f, 0.f, 0.f, 0.f};
            z = __builtin_amdgcn_mfma_f32_16x16x32_bf16(a0, bfrag[nt][0], z, 0, 0, 0);
            z = __builtin_amdgcn_mfma_f32_16x16x32_bf16(a1, bfrag[nt][1], z, 0, 0, 0);
            // C[m][n]: n(col) = lane&15, m(row) = quad*4 + reg
            // -> transposed store: pixel nt*16+l16, rows quad*4..+3, ONE b128
            *(floatx4*)&FbufT[wv][nt * 16 + l16][quad * 4] = z;
        }

        // combine: each lane = one pixel (p = lane), 16 filter rows via
        // 4x ds_read_b128 (in-order DS within the wave orders write->read)
#pragma unroll
        for (int g = 0; g < 4; ++g) {
            floatx4 f4 = *(const floatx4*)&FbufT[wv][lane][g * 4];
#pragma unroll
            for (int rr = 0; rr < 4; ++rr) {
                const int r     = g * 4 + rr;        // all compile-time
                const int idx   = t * 16 + r;
                const int c_rel = idx / 9;
                const int kk    = idx - 9 * c_rel;
                const int di    = kk / 3;
                const int dj    = kk - 3 * di;
                float fv = f4[rr] + bg[obase + r];   // bias: wave-uniform s_load
                fv = fmaxf(fv, 0.f);
                float pv = xb[pb[di][dj] + c_rel * HW];
                if (bad[di][dj]) pv = 0.f;
                oacc[c_rel] = fmaf(fv, pv, oacc[c_rel]);
            }
        }
    }

    float* ob = out + (size_t)b * CC * HW + h * WW + w0 + lane;
#pragma unroll
    for (int i = 0; i < 16; ++i)
        ob[(wv * 16 + i) * HW] = oacc[i];
}

extern "C" void kernel_launch(void* const* d_in, const int* in_sizes, int n_in,
                              void* d_out, int out_size, void* d_ws, size_t ws_size,
                              hipStream_t stream) {
    const float* x  = (const float*)d_in[0];
    const float* Wg = (const float*)d_in[1];
    const float* bg = (const float*)d_in[2];
    float* out = (float*)d_out;
    unsigned short* Wb = (unsigned short*)d_ws;   // 576*64*2 = 73728 B

    ACDA_wconv_kernel<<<dim3((OO * CC + 255) / 256), dim3(256), 0, stream>>>(Wg, Wb);
    ACDA_main_kernel<<<dim3(8 * 128 * 2), dim3(256), 0, stream>>>(x, Wb, bg, out);
}

// Round 4
// 116.751 us; speedup vs baseline: 2.1653x; 1.0161x over previous
//
#include <hip/hip_runtime.h>
#include <hip/hip_bf16.h>

#define CC 64
#define HH 128
#define WW 128
#define OO 576   // C * K * K
#define HW (HH * WW)

typedef __attribute__((ext_vector_type(8))) short short8;
typedef __attribute__((ext_vector_type(4))) float floatx4;

__device__ __forceinline__ unsigned short f2bf(float f) {
    unsigned u = __float_as_uint(f);
    u = (u + 0x7FFFu + ((u >> 16) & 1u)) >> 16;   // RTNE
    return (unsigned short)u;
}

// Pre-convert W_gen (576x64 fp32) -> bf16 in workspace
__global__ void ACDA_wconv_kernel(const float* __restrict__ Wg,
                                  unsigned short* __restrict__ Wb) {
    int i = blockIdx.x * 256 + threadIdx.x;
    if (i < OO * CC) Wb[i] = f2bf(Wg[i]);
}

// 256-thread block = 4 waves; wave wv owns 16 output channels x 64 pixels.
// No __syncthreads: private FbufT slice per wave; intra-wave DS ordering
// guarantees the write->read dependency.
//
// Round-3 post-mortem: latency-bound (wave lifetime ~43.7k cyc vs ~5k
// compute path; occupancy 34%, all pipes <30%). ~300 dependent VMEM ops per
// wave, incl. 144 DIVERGENT bias loads (wv=tid>>6 not provably uniform).
// This round: (1) bias folded into MFMA acc init (144 loads -> 9 float4),
// (2) explicit 2-deep pipeline: chunk t+1's A-frags + bias + 16 patch
// values prefetched into regs during chunk t's combine.
__global__ __launch_bounds__(256) void ACDA_main_kernel(
    const float* __restrict__ x, const unsigned short* __restrict__ Wb,
    const float* __restrict__ bg, float* __restrict__ out)
{
    // Transposed filter buffer: [wave][pixel][filter-row], stride 20 floats.
    // Bank starts for 8 consecutive lanes: (20*l)%32 = {0,20,8,28,16,4,24,12}
    // -> all 32 banks covered, conflict-free on both b128 phases.
    __shared__ float FbufT[4][64][20];   // 20480 B

    const int tid  = threadIdx.x;
    const int lane = tid & 63;
    const int wv   = tid >> 6;       // 16-channel group
    const int quad = lane >> 4;
    const int l16  = lane & 15;

    // Bijective XCD swizzle: 2048 blocks, 8 XCDs, 256 contiguous work items
    // per XCD => each XCD streams one batch image (proven: FETCH 85->17 MB).
    const int bid = blockIdx.x;
    const int wk  = (bid & 7) * 256 + (bid >> 3);
    const int seg = wk & 1;
    const int h   = (wk >> 1) & 127;
    const int b   = wk >> 8;
    const int w0  = seg << 6;

    const float* xb = x + (size_t)b * CC * HW;

    // ---- combine-phase per-lane precompute (clamped cols/rows + kill masks) ----
    int wA = w0 + lane - 1; bool badA = (wA < 0);   if (badA) wA = 0;
    int wB = w0 + lane;
    int wC = w0 + lane + 1; bool badC = (wC > 127); if (badC) wC = 127;
    int rt[3]; bool rbad[3];
#pragma unroll
    for (int di = 0; di < 3; ++di) {
        int rr = h + di - 1;
        rbad[di] = (rr < 0) || (rr > 127);
        rr = rr < 0 ? 0 : (rr > 127 ? 127 : rr);
        rt[di] = rr * WW;
    }
    const int wsel[3]  = {wA, wB, wC};
    const bool wbad[3] = {badA, false, badC};
    const int soffC = wv * 16 * HW;
    int  pb[3][3]; bool bad[3][3];
#pragma unroll
    for (int di = 0; di < 3; ++di)
#pragma unroll
        for (int dj = 0; dj < 3; ++dj) {
            pb[di][dj]  = soffC + rt[di] + wsel[dj];
            bad[di][dj] = rbad[di] || wbad[dj];
        }

    // ---- B fragments (X tile, bf16) in registers for all 9 chunks ----
    // Issued FIRST so chunk-0 MFMA need not drain the later prefetch loads.
    short8 bfrag[4][2];
#pragma unroll
    for (int nt = 0; nt < 4; ++nt) {
#pragma unroll
        for (int ks = 0; ks < 2; ++ks) {
            short8 v;
            const int w = w0 + nt * 16 + l16;
#pragma unroll
            for (int j = 0; j < 8; j += 2) {
                const int c = ks * 32 + quad * 8 + j;
                float f0 = xb[(c * HH + h) * WW + w];
                float f1 = xb[((c + 1) * HH + h) * WW + w];
                __hip_bfloat162 p = __float22bfloat162_rn(make_float2(f0, f1));
                unsigned u;
                __builtin_memcpy(&u, &p, 4);
                v[j]     = (short)(u & 0xffffu);
                v[j + 1] = (short)(u >> 16);
            }
            bfrag[nt][ks] = v;
        }
    }

    float oacc[16];
#pragma unroll
    for (int i = 0; i < 16; ++i) oacc[i] = 0.f;

    // ---- 2-deep pipelined chunk loop (9 chunks of 16 filter rows) ----
    short8 a0A, a1A, a0B, a1B;
    floatx4 bvA, bvB;
    float pvA[16], pvB[16];

    // A-fragments + bias vector for chunk T. bv[reg] = bias of C-row
    // quad*4+reg (aligned float4, uniform within a quad -> broadcast load).
#define LOADA(T, A0, A1, BV) do {                                         \
        const int obase_ = wv * 144 + (T) * 16;                           \
        const unsigned short* wrow_ = Wb + (obase_ + l16) * CC + quad * 8;\
        (A0) = *(const short8*)(wrow_);                                   \
        (A1) = *(const short8*)(wrow_ + 32);                              \
        (BV) = *(const floatx4*)(bg + obase_ + quad * 4);                 \
    } while (0)

    // Patch values for chunk T (all indices compile-time after unroll).
#define LOADP(T, PV) do {                                                 \
        _Pragma("unroll")                                                 \
        for (int r_ = 0; r_ < 16; ++r_) {                                 \
            const int idx_ = (T) * 16 + r_;                               \
            const int c_   = idx_ / 9;                                    \
            const int kk_  = idx_ - 9 * c_;                               \
            const int di_  = kk_ / 3;                                     \
            const int dj_  = kk_ - 3 * di_;                               \
            float v_ = xb[pb[di_][dj_] + c_ * HW];                        \
            (PV)[r_] = bad[di_][dj_] ? 0.f : v_;                          \
        }                                                                 \
    } while (0)

    LOADA(0, a0A, a1A, bvA);
    LOADP(0, pvA);

    // One chunk: MFMA (bias as C-in) -> transposed b128 store -> PREFETCH
    // chunk T+1 -> b128 read -> combine with current patch regs.
#define CHUNK(T, PVC, PVN, A0C, A1C, BVC, A0N, A1N, BVN) do {             \
        _Pragma("unroll")                                                 \
        for (int nt_ = 0; nt_ < 4; ++nt_) {                               \
            floatx4 z_ = (BVC);   /* bias pre-ReLU as accumulator init */ \
            z_ = __builtin_amdgcn_mfma_f32_16x16x32_bf16((A0C), bfrag[nt_][0], z_, 0, 0, 0); \
            z_ = __builtin_amdgcn_mfma_f32_16x16x32_bf16((A1C), bfrag[nt_][1], z_, 0, 0, 0); \
            *(floatx4*)&FbufT[wv][nt_ * 16 + l16][quad * 4] = z_;         \
        }                                                                 \
        if ((T) < 8) {                                                    \
            LOADA((T) + 1, A0N, A1N, BVN);                                \
            LOADP((T) + 1, PVN);                                          \
        }                                                                 \
        _Pragma("unroll")                                                 \
        for (int g_ = 0; g_ < 4; ++g_) {                                  \
            floatx4 f4_ = *(const floatx4*)&FbufT[wv][lane][g_ * 4];      \
            _Pragma("unroll")                                             \
            for (int rr_ = 0; rr_ < 4; ++rr_) {                           \
                const int r_   = g_ * 4 + rr_;                            \
                const int idx_ = (T) * 16 + r_;                           \
                const int c_   = idx_ / 9;                                \
                float fv_ = fmaxf(f4_[rr_], 0.f);                         \
                oacc[c_] = fmaf(fv_, (PVC)[r_], oacc[c_]);                \
            }                                                             \
        }                                                                 \
    } while (0)

    CHUNK(0, pvA, pvB, a0A, a1A, bvA, a0B, a1B, bvB);
    CHUNK(1, pvB, pvA, a0B, a1B, bvB, a0A, a1A, bvA);
    CHUNK(2, pvA, pvB, a0A, a1A, bvA, a0B, a1B, bvB);
    CHUNK(3, pvB, pvA, a0B, a1B, bvB, a0A, a1A, bvA);
    CHUNK(4, pvA, pvB, a0A, a1A, bvA, a0B, a1B, bvB);
    CHUNK(5, pvB, pvA, a0B, a1B, bvB, a0A, a1A, bvA);
    CHUNK(6, pvA, pvB, a0A, a1A, bvA, a0B, a1B, bvB);
    CHUNK(7, pvB, pvA, a0B, a1B, bvB, a0A, a1A, bvA);
    CHUNK(8, pvA, pvB, a0A, a1A, bvA, a0B, a1B, bvB);

#undef CHUNK
#undef LOADP
#undef LOADA

    float* ob = out + (size_t)b * CC * HW + h * WW + w0 + lane;
#pragma unroll
    for (int i = 0; i < 16; ++i)
        ob[(wv * 16 + i) * HW] = oacc[i];
}

extern "C" void kernel_launch(void* const* d_in, const int* in_sizes, int n_in,
                              void* d_out, int out_size, void* d_ws, size_t ws_size,
                              hipStream_t stream) {
    const float* x  = (const float*)d_in[0];
    const float* Wg = (const float*)d_in[1];
    const float* bg = (const float*)d_in[2];
    float* out = (float*)d_out;
    unsigned short* Wb = (unsigned short*)d_ws;   // 576*64*2 = 73728 B

    ACDA_wconv_kernel<<<dim3((OO * CC + 255) / 256), dim3(256), 0, stream>>>(Wg, Wb);
    ACDA_main_kernel<<<dim3(8 * 128 * 2), dim3(256), 0, stream>>>(x, Wb, bg, out);
}

// Round 5
// 112.273 us; speedup vs baseline: 2.2516x; 1.0399x over previous
//
#include <hip/hip_runtime.h>
#include <hip/hip_bf16.h>

#define CC 64
#define HH 128
#define WW 128
#define OO 576   // C * K * K
#define HW (HH * WW)

typedef __attribute__((ext_vector_type(8))) short short8;
typedef __attribute__((ext_vector_type(4))) float floatx4;

__device__ __forceinline__ unsigned short f2bf(float f) {
    unsigned u = __float_as_uint(f);
    u = (u + 0x7FFFu + ((u >> 16) & 1u)) >> 16;   // RTNE
    return (unsigned short)u;
}

// Pre-convert W_gen (576x64 fp32) -> bf16 in workspace
__global__ void ACDA_wconv_kernel(const float* __restrict__ Wg,
                                  unsigned short* __restrict__ Wb) {
    int i = blockIdx.x * 256 + threadIdx.x;
    if (i < OO * CC) Wb[i] = f2bf(Wg[i]);
}

// 256-thread block = 4 waves; wave wv owns 16 output channels x 64 pixels.
//
// R4 post-mortem: ~50us pinned across 3 schedules; L2->L1 traffic ~590MB
// (72KB/wave) is the suspected throughput pin. Biggest redundancy: all 4
// waves loaded the IDENTICAL 16KB B-tile (bfrag never depends on wv) and
// packed it 4x. This round: cooperative B staging -> LDS (bf16), each wave
// loads/packs only its 16-channel quarter; B-LDS unioned with FbufT (dead
// until after fragment reads) so LDS stays 20480B. Two __syncthreads total.
__global__ __launch_bounds__(256) void ACDA_main_kernel(
    const float* __restrict__ x, const unsigned short* __restrict__ Wb,
    const float* __restrict__ bg, float* __restrict__ out)
{
    // Union: Bl (64 px x 72 ch bf16 = 9216B) lives in the same bytes as
    // FbufT[0..1] slices; FbufT first written AFTER all waves finish reading
    // Bl (barrier #2). FbufT row stride 20 floats: bank starts (20*l)%32 =
    // {0,20,8,28,16,4,24,12} -> all 32 banks, conflict-free b128 (measured
    // SQ_LDS_BANK_CONFLICT = 0 in R3/R4).
    __shared__ __align__(16) char smem[20480];
    float (*FbufT)[64][20] = reinterpret_cast<float(*)[64][20]>(smem);          // [4][64][20]
    unsigned short (*Bl)[72] = reinterpret_cast<unsigned short(*)[72]>(smem);   // [64][72]

    const int tid  = threadIdx.x;
    const int lane = tid & 63;
    const int wv   = tid >> 6;       // 16-channel group
    const int quad = lane >> 4;
    const int l16  = lane & 15;

    // Bijective XCD swizzle: 2048 blocks, 8 XCDs, 256 contiguous work items
    // per XCD => each XCD streams one batch image (proven: FETCH 85->17 MB).
    const int bid = blockIdx.x;
    const int wk  = (bid & 7) * 256 + (bid >> 3);
    const int seg = wk & 1;
    const int h   = (wk >> 1) & 127;
    const int b   = wk >> 8;
    const int w0  = seg << 6;

    const float* xb = x + (size_t)b * CC * HW;

    // ---- combine-phase per-lane precompute (clamped cols/rows + kill masks) ----
    int wA = w0 + lane - 1; bool badA = (wA < 0);   if (badA) wA = 0;
    int wB = w0 + lane;
    int wC = w0 + lane + 1; bool badC = (wC > 127); if (badC) wC = 127;
    int rt[3]; bool rbad[3];
#pragma unroll
    for (int di = 0; di < 3; ++di) {
        int rr = h + di - 1;
        rbad[di] = (rr < 0) || (rr > 127);
        rr = rr < 0 ? 0 : (rr > 127 ? 127 : rr);
        rt[di] = rr * WW;
    }
    const int wsel[3]  = {wA, wB, wC};
    const bool wbad[3] = {badA, false, badC};
    const int soffC = wv * 16 * HW;
    int  pb[3][3]; bool bad[3][3];
#pragma unroll
    for (int di = 0; di < 3; ++di)
#pragma unroll
        for (int dj = 0; dj < 3; ++dj) {
            pb[di][dj]  = soffC + rt[di] + wsel[dj];
            bad[di][dj] = rbad[di] || wbad[dj];
        }

    // ---- cooperative B-tile staging: wave wv packs channels [wv*16,+16) ----
    // lane = pixel; 16 coalesced f32 loads + 8 cvt_pk + 8 ds_write_b32.
    {
        const int w = w0 + lane;
#pragma unroll
        for (int cc = 0; cc < 16; cc += 2) {
            const int c = wv * 16 + cc;
            float f0 = xb[(c * HH + h) * WW + w];
            float f1 = xb[((c + 1) * HH + h) * WW + w];
            __hip_bfloat162 p = __float22bfloat162_rn(make_float2(f0, f1));
            unsigned u;
            __builtin_memcpy(&u, &p, 4);
            *(unsigned*)&Bl[lane][c] = u;
        }
    }

    float oacc[16];
#pragma unroll
    for (int i = 0; i < 16; ++i) oacc[i] = 0.f;

    short8 a0A, a1A, a0B, a1B;
    floatx4 bvA, bvB;
    float pvA[16], pvB[16];

#define LOADA(T, A0, A1, BV) do {                                         \
        const int obase_ = wv * 144 + (T) * 16;                           \
        const unsigned short* wrow_ = Wb + (obase_ + l16) * CC + quad * 8;\
        (A0) = *(const short8*)(wrow_);                                   \
        (A1) = *(const short8*)(wrow_ + 32);                              \
        (BV) = *(const floatx4*)(bg + obase_ + quad * 4);                 \
    } while (0)

#define LOADP(T, PV) do {                                                 \
        _Pragma("unroll")                                                 \
        for (int r_ = 0; r_ < 16; ++r_) {                                 \
            const int idx_ = (T) * 16 + r_;                               \
            const int c_   = idx_ / 9;                                    \
            const int kk_  = idx_ - 9 * c_;                               \
            const int di_  = kk_ / 3;                                     \
            const int dj_  = kk_ - 3 * di_;                               \
            float v_ = xb[pb[di_][dj_] + c_ * HW];                        \
            (PV)[r_] = bad[di_][dj_] ? 0.f : v_;                          \
        }                                                                 \
    } while (0)

    // Issue chunk-0 global prefetch BEFORE the barriers so its latency hides
    // under barrier + fragment reads.
    LOADA(0, a0A, a1A, bvA);
    LOADP(0, pvA);

    __syncthreads();   // Bl fully written (waitcnt+barrier)

    // ---- B fragments from LDS (shared across the 4 waves) ----
    // bfrag[nt][ks][j] = bf16 x[ks*32+quad*8+j][h][w0+nt*16+l16]
    short8 bfrag[4][2];
#pragma unroll
    for (int nt = 0; nt < 4; ++nt)
#pragma unroll
        for (int ks = 0; ks < 2; ++ks)
            bfrag[nt][ks] = *(const short8*)&Bl[nt * 16 + l16][ks * 32 + quad * 8];

    __syncthreads();   // all waves done reading Bl; FbufT may now overwrite it

    // One chunk: MFMA (bias as C-in) -> transposed b128 store -> PREFETCH
    // chunk T+1 -> b128 read -> combine with current patch regs.
#define CHUNK(T, PVC, PVN, A0C, A1C, BVC, A0N, A1N, BVN) do {             \
        _Pragma("unroll")                                                 \
        for (int nt_ = 0; nt_ < 4; ++nt_) {                               \
            floatx4 z_ = (BVC);   /* bias pre-ReLU as accumulator init */ \
            z_ = __builtin_amdgcn_mfma_f32_16x16x32_bf16((A0C), bfrag[nt_][0], z_, 0, 0, 0); \
            z_ = __builtin_amdgcn_mfma_f32_16x16x32_bf16((A1C), bfrag[nt_][1], z_, 0, 0, 0); \
            *(floatx4*)&FbufT[wv][nt_ * 16 + l16][quad * 4] = z_;         \
        }                                                                 \
        if ((T) < 8) {                                                    \
            LOADA((T) + 1, A0N, A1N, BVN);                                \
            LOADP((T) + 1, PVN);                                          \
        }                                                                 \
        _Pragma("unroll")                                                 \
        for (int g_ = 0; g_ < 4; ++g_) {                                  \
            floatx4 f4_ = *(const floatx4*)&FbufT[wv][lane][g_ * 4];      \
            _Pragma("unroll")                                             \
            for (int rr_ = 0; rr_ < 4; ++rr_) {                           \
                const int r_   = g_ * 4 + rr_;                            \
                const int idx_ = (T) * 16 + r_;                           \
                const int c_   = idx_ / 9;                                \
                float fv_ = fmaxf(f4_[rr_], 0.f);                         \
                oacc[c_] = fmaf(fv_, (PVC)[r_], oacc[c_]);                \
            }                                                             \
        }                                                                 \
    } while (0)

    CHUNK(0, pvA, pvB, a0A, a1A, bvA, a0B, a1B, bvB);
    CHUNK(1, pvB, pvA, a0B, a1B, bvB, a0A, a1A, bvA);
    CHUNK(2, pvA, pvB, a0A, a1A, bvA, a0B, a1B, bvB);
    CHUNK(3, pvB, pvA, a0B, a1B, bvB, a0A, a1A, bvA);
    CHUNK(4, pvA, pvB, a0A, a1A, bvA, a0B, a1B, bvB);
    CHUNK(5, pvB, pvA, a0B, a1B, bvB, a0A, a1A, bvA);
    CHUNK(6, pvA, pvB, a0A, a1A, bvA, a0B, a1B, bvB);
    CHUNK(7, pvB, pvA, a0B, a1B, bvB, a0A, a1A, bvA);
    CHUNK(8, pvA, pvB, a0A, a1A, bvA, a0B, a1B, bvB);

#undef CHUNK
#undef LOADP
#undef LOADA

    float* ob = out + (size_t)b * CC * HW + h * WW + w0 + lane;
#pragma unroll
    for (int i = 0; i < 16; ++i)
        ob[(wv * 16 + i) * HW] = oacc[i];
}

extern "C" void kernel_launch(void* const* d_in, const int* in_sizes, int n_in,
                              void* d_out, int out_size, void* d_ws, size_t ws_size,
                              hipStream_t stream) {
    const float* x  = (const float*)d_in[0];
    const float* Wg = (const float*)d_in[1];
    const float* bg = (const float*)d_in[2];
    float* out = (float*)d_out;
    unsigned short* Wb = (unsigned short*)d_ws;   // 576*64*2 = 73728 B

    ACDA_wconv_kernel<<<dim3((OO * CC + 255) / 256), dim3(256), 0, stream>>>(Wg, Wb);
    ACDA_main_kernel<<<dim3(8 * 128 * 2), dim3(256), 0, stream>>>(x, Wb, bg, out);
}